// Round 5
// baseline (397.631 us; speedup 1.0000x reference)
//
#include <hip/hip_runtime.h>
#include <hip/hip_bf16.h>

#define NNODES 10000
#define NROWP  10112   // NNODES padded to multiple of 128 (GEMM tile)
#define NEDGES 160000
#define ETOT   (NEDGES + NNODES)
#define CIN    256
#define CH     512     // HID*H
#define NHEAD  8
#define HDIM   64
#define COUT   16
#define NEG_SLOPE 0.2f

// ---------- bf16 helpers (bit-level, round-to-nearest-even) ----------
__device__ __forceinline__ float bf2f(uint u) {
    union { uint i; float f; } v; v.i = u << 16; return v.f;
}
__device__ __forceinline__ ushort f2bf(float x) {
    union { float f; uint i; } v; v.f = x;
    uint r = v.i + 0x7fff + ((v.i >> 16) & 1);
    return (ushort)(r >> 16);
}

typedef __attribute__((ext_vector_type(8))) short short8v;
typedef __attribute__((ext_vector_type(4))) float f32x4;

// ---------------- CSR build ----------------
__global__ void count_deg_k(const int* __restrict__ ei, int* __restrict__ deg) {
    int eid = blockIdx.x * 256 + threadIdx.x;
    if (eid >= ETOT) return;
    int dst = (eid < NEDGES) ? ei[NEDGES + eid] : (eid - NEDGES);
    atomicAdd(&deg[dst], 1);
}

__global__ __launch_bounds__(512) void scan_k(const int* __restrict__ deg, int* __restrict__ startA) {
    __shared__ int partial[512];
    int t = threadIdx.x;
    const int per = (NNODES + 511) / 512;  // 20
    int base = t * per;
    int s = 0;
    for (int j = 0; j < per; ++j) { int idx = base + j; if (idx < NNODES) s += deg[idx]; }
    partial[t] = s;
    __syncthreads();
    for (int off = 1; off < 512; off <<= 1) {
        int v = (t >= off) ? partial[t - off] : 0;
        __syncthreads();
        partial[t] += v;
        __syncthreads();
    }
    int run = (t == 0) ? 0 : partial[t - 1];
    for (int j = 0; j < per; ++j) {
        int idx = base + j;
        if (idx < NNODES) { startA[idx] = run; run += deg[idx]; }
    }
}

__global__ void scatter_k(const int* __restrict__ ei, const int* __restrict__ startA,
                          int* __restrict__ cursor, int* __restrict__ csr_src) {
    int eid = blockIdx.x * 256 + threadIdx.x;
    if (eid >= ETOT) return;
    int src, dst;
    if (eid < NEDGES) { src = ei[eid]; dst = ei[NEDGES + eid]; }
    else { src = dst = eid - NEDGES; }
    int pos = startA[dst] + atomicAdd(&cursor[dst], 1);
    csr_src[pos] = src;
}

// ---------------- converts ----------------
__global__ void convert_x_k(const float* __restrict__ x, ushort* __restrict__ xb) {
    int idx = blockIdx.x * 256 + threadIdx.x;
    if (idx >= NNODES * CIN / 4) return;
    float4 v = ((const float4*)x)[idx];
    ushort4 o; o.x = f2bf(v.x); o.y = f2bf(v.y); o.z = f2bf(v.z); o.w = f2bf(v.w);
    ((ushort4*)xb)[idx] = o;
}

// W[K][N] fp32 -> Wt[N][K] bf16, 32x32 LDS tile transpose
__global__ __launch_bounds__(256) void convert_wT_k(const float* __restrict__ W, ushort* __restrict__ Wt,
                                                    int K, int N) {
    __shared__ float tile[32][33];
    int tx = threadIdx.x & 31, ty = threadIdx.x >> 5;  // 32x8
    int n0 = blockIdx.x * 32, k0 = blockIdx.y * 32;
#pragma unroll
    for (int r = 0; r < 32; r += 8)
        tile[ty + r][tx] = W[(size_t)(k0 + ty + r) * N + n0 + tx];
    __syncthreads();
#pragma unroll
    for (int r = 0; r < 32; r += 8)
        Wt[(size_t)(n0 + ty + r) * K + k0 + tx] = f2bf(tile[tx][ty + r]);
}

// ---------------- bf16 MFMA GEMM (m97 structure): C[M,CH] = A @ Bt^T (+bias) -----------
// 128x128 tile, 4 waves (2x2), each wave 64x64 = 4x4 frags of 16x16x32.
// LDS linear [128][32] (global_load_lds needs linear dest); A rows padded to NROWP.
__global__ __launch_bounds__(256) void gemm_mfma128(const ushort* __restrict__ A,
                                                    const ushort* __restrict__ Bt,
                                                    const float* __restrict__ bias,
                                                    ushort* __restrict__ C, int M, int K) {
    __shared__ __align__(16) ushort Asl[128 * 32];
    __shared__ __align__(16) ushort Bsl[128 * 32];
    int t = threadIdx.x;
    int wid = t >> 6, lane = t & 63;
    int row0 = blockIdx.x * 128, col0 = blockIdx.y * 128;
    int wr = (wid >> 1) * 64, wc = (wid & 1) * 64;
    f32x4 acc[4][4] = {};
    // staging: chunk c = row*4 + kg (16B each); thread t owns chunks t and t+256
    int c0row = t >> 2, c0kg = t & 3;
    const ushort* Ag0 = A + (size_t)(row0 + c0row) * K + c0kg * 8;
    const ushort* Ag1 = A + (size_t)(row0 + 64 + c0row) * K + c0kg * 8;
    const ushort* Bg0 = Bt + (size_t)(col0 + c0row) * K + c0kg * 8;
    const ushort* Bg1 = Bt + (size_t)(col0 + 64 + c0row) * K + c0kg * 8;
    int lr = lane & 15, kg = lane >> 4;

    for (int k0 = 0; k0 < K; k0 += 32) {
        __builtin_amdgcn_global_load_lds(
            (const __attribute__((address_space(1))) uint*)(const void*)(Ag0 + k0),
            (__attribute__((address_space(3))) uint*)&Asl[t * 8], 16, 0, 0);
        __builtin_amdgcn_global_load_lds(
            (const __attribute__((address_space(1))) uint*)(const void*)(Ag1 + k0),
            (__attribute__((address_space(3))) uint*)&Asl[(t + 256) * 8], 16, 0, 0);
        __builtin_amdgcn_global_load_lds(
            (const __attribute__((address_space(1))) uint*)(const void*)(Bg0 + k0),
            (__attribute__((address_space(3))) uint*)&Bsl[t * 8], 16, 0, 0);
        __builtin_amdgcn_global_load_lds(
            (const __attribute__((address_space(1))) uint*)(const void*)(Bg1 + k0),
            (__attribute__((address_space(3))) uint*)&Bsl[(t + 256) * 8], 16, 0, 0);
        __syncthreads();  // drains vmcnt -> LDS tiles ready
        short8v af[4], bfr[4];
#pragma unroll
        for (int i = 0; i < 4; ++i) {
            af[i]  = *(const short8v*)&Asl[(wr + i * 16 + lr) * 32 + kg * 8];
            bfr[i] = *(const short8v*)&Bsl[(wc + i * 16 + lr) * 32 + kg * 8];
        }
#pragma unroll
        for (int i = 0; i < 4; ++i)
#pragma unroll
            for (int j = 0; j < 4; ++j)
                acc[i][j] = __builtin_amdgcn_mfma_f32_16x16x32_bf16(af[i], bfr[j], acc[i][j], 0, 0, 0);
        __syncthreads();  // protect LDS before next iteration's staging
    }
    // C/D layout: col = lane&15, row = (lane>>4)*4 + q   [m89-verified]
#pragma unroll
    for (int j = 0; j < 4; ++j) {
        int c = col0 + wc + j * 16 + lr;
        float bb = bias ? bias[c] : 0.f;
#pragma unroll
        for (int i = 0; i < 4; ++i) {
#pragma unroll
            for (int q = 0; q < 4; ++q) {
                int r = row0 + wr + i * 16 + kg * 4 + q;
                if (r < M) C[(size_t)r * CH + c] = f2bf(acc[i][j][q] + bb);
            }
        }
    }
}

// ---------------- LN + ELU on bf16 (128 thr, 4 ch/thread) ----------------
__global__ __launch_bounds__(128) void ln_elu_k(const ushort* __restrict__ inb, const float* __restrict__ g,
                                                const float* __restrict__ b, ushort* __restrict__ outb) {
    int i = blockIdx.x, t = threadIdx.x;
    uint2 hv = ((const uint2*)(inb + (size_t)i * CH))[t];
    float a0 = bf2f(hv.x & 0xffff), a1 = bf2f(hv.x >> 16);
    float a2 = bf2f(hv.y & 0xffff), a3 = bf2f(hv.y >> 16);
    float s = a0 + a1 + a2 + a3;
    float s2 = a0 * a0 + a1 * a1 + a2 * a2 + a3 * a3;
#pragma unroll
    for (int off = 1; off < 64; off <<= 1) { s += __shfl_xor(s, off); s2 += __shfl_xor(s2, off); }
    __shared__ float sh[4];
    int wid = t >> 6, lane = t & 63;
    if (lane == 0) { sh[wid] = s; sh[2 + wid] = s2; }
    __syncthreads();
    float tot = sh[0] + sh[1], tot2 = sh[2] + sh[3];
    float mean = tot * (1.0f / CH);
    float var = tot2 * (1.0f / CH) - mean * mean;
    float rstd = rsqrtf(var + 1e-5f);
    float4 gv = ((const float4*)g)[t];
    float4 bv = ((const float4*)b)[t];
    float y0 = (a0 - mean) * rstd * gv.x + bv.x; y0 = y0 > 0.f ? y0 : __expf(y0) - 1.f;
    float y1 = (a1 - mean) * rstd * gv.y + bv.y; y1 = y1 > 0.f ? y1 : __expf(y1) - 1.f;
    float y2 = (a2 - mean) * rstd * gv.z + bv.z; y2 = y2 > 0.f ? y2 : __expf(y2) - 1.f;
    float y3 = (a3 - mean) * rstd * gv.w + bv.w; y3 = y3 > 0.f ? y3 : __expf(y3) - 1.f;
    ushort4 o; o.x = f2bf(y0); o.y = f2bf(y1); o.z = f2bf(y2); o.w = f2bf(y3);
    ((ushort4*)(outb + (size_t)i * CH))[t] = o;
}

// ---------------- attention logits (8 heads, bf16 h) ----------------
__global__ void attn_logits_k(const ushort* __restrict__ h, const float* __restrict__ a_src,
                              const float* __restrict__ a_dst, float* __restrict__ als,
                              float* __restrict__ ald) {
    int idx = blockIdx.x * 256 + threadIdx.x;
    if (idx >= NNODES * NHEAD) return;
    int i = idx >> 3, hh = idx & 7;
    const uint2* hp = (const uint2*)(h + (size_t)i * CH + hh * HDIM);
    const float* sp = a_src + hh * HDIM;
    const float* dp = a_dst + hh * HDIM;
    float s = 0.f, d = 0.f;
#pragma unroll
    for (int j = 0; j < HDIM / 4; ++j) {
        uint2 v = hp[j];
        float h0 = bf2f(v.x & 0xffff), h1 = bf2f(v.x >> 16);
        float h2 = bf2f(v.y & 0xffff), h3 = bf2f(v.y >> 16);
        s += h0 * sp[j * 4] + h1 * sp[j * 4 + 1] + h2 * sp[j * 4 + 2] + h3 * sp[j * 4 + 3];
        d += h0 * dp[j * 4] + h1 * dp[j * 4 + 1] + h2 * dp[j * 4 + 2] + h3 * dp[j * 4 + 3];
    }
    als[idx] = s; ald[idx] = d;
}

// ---------------- per-(node,head) softmax: un-normalized p per edge + 1/sum ----------------
template <int H>
__global__ void alpha_k(const float* __restrict__ als, const float* __restrict__ ald,
                        const int* __restrict__ startA, const int* __restrict__ deg,
                        const int* __restrict__ csr, float* __restrict__ palpha,
                        float* __restrict__ invs) {
    int idx = blockIdx.x * 256 + threadIdx.x;
    if (idx >= NNODES * H) return;
    int i = idx / H, hh = idx % H;
    int s0 = startA[i], d = deg[i];
    float aldv = ald[idx];
    float m = -1e30f;
    for (int e = 0; e < d; ++e) {
        int src = csr[s0 + e];
        float ee = als[src * H + hh] + aldv;
        ee = ee > 0.f ? ee : NEG_SLOPE * ee;
        m = fmaxf(m, ee);
    }
    float s = 0.f;
    for (int e = 0; e < d; ++e) {
        int src = csr[s0 + e];
        float ee = als[src * H + hh] + aldv;
        ee = ee > 0.f ? ee : NEG_SLOPE * ee;
        float p = __expf(ee - m);
        s += p;
        palpha[(size_t)(s0 + e) * H + hh] = p;
    }
    invs[idx] = 1.0f / (s + 1e-16f);
}

// ---------------- gather + bias + LN + ELU + residual (bf16, 128 thr, 4 ch/thread) --------
__global__ __launch_bounds__(128) void agg_ln_k(const ushort* __restrict__ hb, const float* __restrict__ palpha,
                                                const float* __restrict__ invs, const int* __restrict__ startA,
                                                const int* __restrict__ deg, const int* __restrict__ csr,
                                                const float* __restrict__ bias, const float* __restrict__ gamma,
                                                const float* __restrict__ beta, const ushort* __restrict__ residb,
                                                ushort* __restrict__ outb) {
    int i = blockIdx.x, t = threadIdx.x;
    int c0 = t * 4, head = t >> 4;
    int s0 = startA[i], d = deg[i];
    const float* pa = palpha + (size_t)s0 * NHEAD + head;
    const int* cp = csr + s0;
    float a0 = 0.f, a1 = 0.f, a2 = 0.f, a3 = 0.f;
    for (int e = 0; e < d; ++e) {
        int src = cp[e];
        float p = pa[(size_t)e * NHEAD];
        uint2 hv = *(const uint2*)(hb + (size_t)src * CH + c0);
        a0 += p * bf2f(hv.x & 0xffff); a1 += p * bf2f(hv.x >> 16);
        a2 += p * bf2f(hv.y & 0xffff); a3 += p * bf2f(hv.y >> 16);
    }
    float inv = invs[i * NHEAD + head];
    float4 bi = ((const float4*)bias)[t];
    a0 = a0 * inv + bi.x; a1 = a1 * inv + bi.y; a2 = a2 * inv + bi.z; a3 = a3 * inv + bi.w;
    float s = a0 + a1 + a2 + a3;
    float s2 = a0 * a0 + a1 * a1 + a2 * a2 + a3 * a3;
#pragma unroll
    for (int off = 1; off < 64; off <<= 1) { s += __shfl_xor(s, off); s2 += __shfl_xor(s2, off); }
    __shared__ float sh[4];
    int wid = t >> 6, lane = t & 63;
    if (lane == 0) { sh[wid] = s; sh[2 + wid] = s2; }
    __syncthreads();
    float tot = sh[0] + sh[1], tot2 = sh[2] + sh[3];
    float mean = tot * (1.0f / CH);
    float var = tot2 * (1.0f / CH) - mean * mean;
    float rstd = rsqrtf(var + 1e-5f);
    float4 gv = ((const float4*)gamma)[t];
    float4 bv = ((const float4*)beta)[t];
    uint2 rv = ((const uint2*)(residb + (size_t)i * CH))[t];
    float y0 = (a0 - mean) * rstd * gv.x + bv.x; y0 = (y0 > 0.f ? y0 : __expf(y0) - 1.f) + bf2f(rv.x & 0xffff);
    float y1 = (a1 - mean) * rstd * gv.y + bv.y; y1 = (y1 > 0.f ? y1 : __expf(y1) - 1.f) + bf2f(rv.x >> 16);
    float y2 = (a2 - mean) * rstd * gv.z + bv.z; y2 = (y2 > 0.f ? y2 : __expf(y2) - 1.f) + bf2f(rv.y & 0xffff);
    float y3 = (a3 - mean) * rstd * gv.w + bv.w; y3 = (y3 > 0.f ? y3 : __expf(y3) - 1.f) + bf2f(rv.y >> 16);
    ushort4 o; o.x = f2bf(y0); o.y = f2bf(y1); o.z = f2bf(y2); o.w = f2bf(y3);
    ((ushort4*)(outb + (size_t)i * CH))[t] = o;
}

// ---------------- small GEMM: h3[M,16] = A[M,512](bf16) @ W3[512,16](fp32) ----------------
__global__ __launch_bounds__(256) void gemm_small_k(const ushort* __restrict__ A, const float* __restrict__ W,
                                                    float* __restrict__ C) {
    int col = threadIdx.x & 15;
    int row = blockIdx.x * 16 + (threadIdx.x >> 4);
    if (row >= NNODES) return;
    const ushort* ar = A + (size_t)row * CH;
    float acc = 0.f;
#pragma unroll 8
    for (int k = 0; k < CH; k += 2) {
        uint av = *(const uint*)(ar + k);
        acc += bf2f(av & 0xffff) * W[k * COUT + col];
        acc += bf2f(av >> 16) * W[(k + 1) * COUT + col];
    }
    C[row * COUT + col] = acc;
}

// ---------------- head=1 logits (fp32 h3) ----------------
__global__ void attn_logits1_k(const float* __restrict__ h3, const float* __restrict__ as3,
                               const float* __restrict__ ad3, float* __restrict__ als3,
                               float* __restrict__ ald3) {
    int i = blockIdx.x * 256 + threadIdx.x;
    if (i >= NNODES) return;
    float s = 0.f, d = 0.f;
#pragma unroll
    for (int c = 0; c < COUT; ++c) {
        float v = h3[i * COUT + c];
        s += v * as3[c]; d += v * ad3[c];
    }
    als3[i] = s; ald3[i] = d;
}

// ---------------- final gather + bias + LN (16 ch, 1 head) ----------------
__global__ __launch_bounds__(256) void agg16_k(const float* __restrict__ h3, const float* __restrict__ palpha3,
                                               const float* __restrict__ invs3, const int* __restrict__ startA,
                                               const int* __restrict__ deg, const int* __restrict__ csr,
                                               const float* __restrict__ b3, const float* __restrict__ g3,
                                               const float* __restrict__ be3, float* __restrict__ out) {
    int t = threadIdx.x;
    int i = blockIdx.x * 16 + (t >> 4);
    int c = t & 15;
    if (i >= NNODES) return;
    int s0 = startA[i], d = deg[i];
    float acc = 0.f;
    for (int e = 0; e < d; ++e) {
        int pos = s0 + e;
        acc += palpha3[pos] * h3[csr[pos] * COUT + c];
    }
    acc = acc * invs3[i] + b3[c];
    float v = acc, v2 = acc * acc;
#pragma unroll
    for (int off = 1; off < 16; off <<= 1) { v += __shfl_xor(v, off, 16); v2 += __shfl_xor(v2, off, 16); }
    float mean = v * (1.0f / COUT);
    float var = v2 * (1.0f / COUT) - mean * mean;
    out[i * COUT + c] = (acc - mean) * rsqrtf(var + 1e-5f) * g3[c] + be3[c];
}

extern "C" void kernel_launch(void* const* d_in, const int* in_sizes, int n_in,
                              void* d_out, int out_size, void* d_ws, size_t ws_size,
                              hipStream_t stream) {
    const float* x   = (const float*)d_in[0];
    const int*   ei  = (const int*)d_in[1];
    const float* Wp  = (const float*)d_in[2];
    const float* bp  = (const float*)d_in[3];
    const float* g0  = (const float*)d_in[4];
    const float* b0  = (const float*)d_in[5];
    const float* W1  = (const float*)d_in[6];
    const float* as1 = (const float*)d_in[7];
    const float* ad1 = (const float*)d_in[8];
    const float* b1  = (const float*)d_in[9];
    const float* g1  = (const float*)d_in[10];
    const float* be1 = (const float*)d_in[11];
    const float* W2  = (const float*)d_in[12];
    const float* as2 = (const float*)d_in[13];
    const float* ad2 = (const float*)d_in[14];
    const float* b2  = (const float*)d_in[15];
    const float* g2  = (const float*)d_in[16];
    const float* be2 = (const float*)d_in[17];
    const float* W3  = (const float*)d_in[18];
    const float* as3 = (const float*)d_in[19];
    const float* ad3 = (const float*)d_in[20];
    const float* b3  = (const float*)d_in[21];
    const float* g3  = (const float*)d_in[22];
    const float* be3 = (const float*)d_in[23];

    // ---- workspace carve (~47 MB); activation buffers padded to NROWP rows ----
    const size_t NFP = (size_t)NROWP * CH;
    ushort* B0  = (ushort*)d_ws;
    ushort* B1  = B0 + NFP;
    ushort* B2  = B1 + NFP;
    ushort* xbf = B2 + NFP;                      // NROWP*CIN
    ushort* Wpt = xbf + (size_t)NROWP * CIN;     // CIN*CH
    ushort* W1t = Wpt + (size_t)CIN * CH;        // CH*CH
    ushort* W2t = W1t + (size_t)CH * CH;
    float* als     = (float*)(W2t + (size_t)CH * CH);
    float* ald     = als + NNODES * NHEAD;
    float* palpha  = ald + NNODES * NHEAD;       // ETOT*NHEAD
    float* invs    = palpha + (size_t)ETOT * NHEAD;
    float* h3      = invs + NNODES * NHEAD;      // NNODES*COUT
    float* als3    = h3 + (size_t)NNODES * COUT;
    float* ald3    = als3 + NNODES;
    float* palpha3 = ald3 + NNODES;              // ETOT
    float* invs3   = palpha3 + ETOT;
    int* deg = (int*)(invs3 + NNODES);
    int* stA = deg + NNODES;
    int* cur = stA + NNODES;
    int* csr = cur + NNODES;

    // ---- CSR build ----
    hipMemsetAsync(deg, 0, NNODES * sizeof(int), stream);
    hipMemsetAsync(cur, 0, NNODES * sizeof(int), stream);
    count_deg_k<<<(ETOT + 255) / 256, 256, 0, stream>>>(ei, deg);
    scan_k<<<1, 512, 0, stream>>>(deg, stA);
    scatter_k<<<(ETOT + 255) / 256, 256, 0, stream>>>(ei, stA, cur, csr);

    // ---- converts ----
    convert_x_k<<<(NNODES * CIN / 4 + 255) / 256, 256, 0, stream>>>(x, xbf);
    convert_wT_k<<<dim3(CH / 32, CIN / 32), 256, 0, stream>>>(Wp, Wpt, CIN, CH);
    convert_wT_k<<<dim3(CH / 32, CH / 32), 256, 0, stream>>>(W1, W1t, CH, CH);
    convert_wT_k<<<dim3(CH / 32, CH / 32), 256, 0, stream>>>(W2, W2t, CH, CH);

    dim3 gg(NROWP / 128, CH / 128);  // 79 x 4

    // ---- input projection + LN + ELU ----
    gemm_mfma128<<<gg, 256, 0, stream>>>(xbf, Wpt, bp, B0, NNODES, CIN);
    ln_elu_k<<<NNODES, 128, 0, stream>>>(B0, g0, b0, B1);

    // ---- GAT layer 1: h=gemm(B1) -> B2; agg(resid=B1) -> B0 ----
    gemm_mfma128<<<gg, 256, 0, stream>>>(B1, W1t, nullptr, B2, NNODES, CH);
    attn_logits_k<<<(NNODES * NHEAD + 255) / 256, 256, 0, stream>>>(B2, as1, ad1, als, ald);
    alpha_k<NHEAD><<<(NNODES * NHEAD + 255) / 256, 256, 0, stream>>>(als, ald, stA, deg, csr, palpha, invs);
    agg_ln_k<<<NNODES, 128, 0, stream>>>(B2, palpha, invs, stA, deg, csr, b1, g1, be1, B1, B0);

    // ---- GAT layer 2: h=gemm(B0) -> B1; agg(resid=B0) -> B2 ----
    gemm_mfma128<<<gg, 256, 0, stream>>>(B0, W2t, nullptr, B1, NNODES, CH);
    attn_logits_k<<<(NNODES * NHEAD + 255) / 256, 256, 0, stream>>>(B1, as2, ad2, als, ald);
    alpha_k<NHEAD><<<(NNODES * NHEAD + 255) / 256, 256, 0, stream>>>(als, ald, stA, deg, csr, palpha, invs);
    agg_ln_k<<<NNODES, 128, 0, stream>>>(B1, palpha, invs, stA, deg, csr, b2, g2, be2, B0, B2);

    // ---- final layer (B2 -> d_out) ----
    gemm_small_k<<<(NNODES + 15) / 16, 256, 0, stream>>>(B2, W3, h3);
    attn_logits1_k<<<(NNODES + 255) / 256, 256, 0, stream>>>(h3, as3, ad3, als3, ald3);
    alpha_k<1><<<(NNODES + 255) / 256, 256, 0, stream>>>(als3, ald3, stA, deg, csr, palpha3, invs3);
    agg16_k<<<(NNODES + 15) / 16, 256, 0, stream>>>(h3, palpha3, invs3, stA, deg, csr, b3, g3, be3, (float*)d_out);
}

// Round 6
// 367.288 us; speedup vs baseline: 1.0826x; 1.0826x over previous
//
#include <hip/hip_runtime.h>
#include <hip/hip_bf16.h>

#define NNODES 10000
#define NEDGES 160000
#define ETOT   (NEDGES + NNODES)
#define CIN    256
#define CH     512     // HID*H
#define NHEAD  8
#define HDIM   64
#define COUT   16
#define NEG_SLOPE 0.2f
#define NF ((size_t)NNODES * CH)

// ---------- bf16 helpers (bit-level, round-to-nearest-even) ----------
__device__ __forceinline__ float bf2f(uint u) {
    union { uint i; float f; } v; v.i = u << 16; return v.f;
}
__device__ __forceinline__ ushort f2bf(float x) {
    union { float f; uint i; } v; v.f = x;
    uint r = v.i + 0x7fff + ((v.i >> 16) & 1);
    return (ushort)(r >> 16);
}

typedef __attribute__((ext_vector_type(8))) short short8v;
typedef __attribute__((ext_vector_type(4))) float f32x4;

// ---------------- CSR build ----------------
__global__ void count_deg_k(const int* __restrict__ ei, int* __restrict__ deg) {
    int eid = blockIdx.x * 256 + threadIdx.x;
    if (eid >= ETOT) return;
    int dst = (eid < NEDGES) ? ei[NEDGES + eid] : (eid - NEDGES);
    atomicAdd(&deg[dst], 1);
}

__global__ __launch_bounds__(512) void scan_k(const int* __restrict__ deg, int* __restrict__ startA) {
    __shared__ int partial[512];
    int t = threadIdx.x;
    const int per = (NNODES + 511) / 512;  // 20
    int base = t * per;
    int s = 0;
    for (int j = 0; j < per; ++j) { int idx = base + j; if (idx < NNODES) s += deg[idx]; }
    partial[t] = s;
    __syncthreads();
    for (int off = 1; off < 512; off <<= 1) {
        int v = (t >= off) ? partial[t - off] : 0;
        __syncthreads();
        partial[t] += v;
        __syncthreads();
    }
    int run = (t == 0) ? 0 : partial[t - 1];
    for (int j = 0; j < per; ++j) {
        int idx = base + j;
        if (idx < NNODES) { startA[idx] = run; run += deg[idx]; }
    }
}

__global__ void scatter_k(const int* __restrict__ ei, const int* __restrict__ startA,
                          int* __restrict__ cursor, int* __restrict__ csr_src) {
    int eid = blockIdx.x * 256 + threadIdx.x;
    if (eid >= ETOT) return;
    int src, dst;
    if (eid < NEDGES) { src = ei[eid]; dst = ei[NEDGES + eid]; }
    else { src = dst = eid - NEDGES; }
    int pos = startA[dst] + atomicAdd(&cursor[dst], 1);
    csr_src[pos] = src;
}

// ---------------- converts ----------------
__global__ void convert_x_k(const float* __restrict__ x, ushort* __restrict__ xb) {
    int idx = blockIdx.x * 256 + threadIdx.x;
    if (idx >= NNODES * CIN / 4) return;
    float4 v = ((const float4*)x)[idx];
    ushort4 o; o.x = f2bf(v.x); o.y = f2bf(v.y); o.z = f2bf(v.z); o.w = f2bf(v.w);
    ((ushort4*)xb)[idx] = o;
}

// W[K][N] fp32 -> Wt[N][K] bf16, 32x32 LDS tile transpose
__global__ __launch_bounds__(256) void convert_wT_k(const float* __restrict__ W, ushort* __restrict__ Wt,
                                                    int K, int N) {
    __shared__ float tile[32][33];
    int tx = threadIdx.x & 31, ty = threadIdx.x >> 5;  // 32x8
    int n0 = blockIdx.x * 32, k0 = blockIdx.y * 32;
#pragma unroll
    for (int r = 0; r < 32; r += 8)
        tile[ty + r][tx] = W[(size_t)(k0 + ty + r) * N + n0 + tx];
    __syncthreads();
#pragma unroll
    for (int r = 0; r < 32; r += 8)
        Wt[(size_t)(n0 + ty + r) * K + k0 + tx] = f2bf(tile[tx][ty + r]);
}

// ---------------- bf16 MFMA GEMM: C[M,CH] = A[M,K] @ Bt[CH,K]^T (+bias), bf16 out ----------
// 64x64 tile, 4 waves (2x2), 16x16x32 MFMA, BK=32  [round-4 measured-best for N=512]
#define LDK 40  // padded LDS row (bf16 elems): 80B stride
__global__ __launch_bounds__(256) void gemm_mfma(const ushort* __restrict__ A, const ushort* __restrict__ Bt,
                                                 const float* __restrict__ bias, ushort* __restrict__ C,
                                                 int M, int K) {
    __shared__ ushort Asl[64 * LDK];
    __shared__ ushort Bsl[64 * LDK];
    int t = threadIdx.x;
    int wid = t >> 6, lane = t & 63;
    int row0 = blockIdx.x * 64, col0 = blockIdx.y * 64;
    int wr = (wid >> 1) * 32, wc = (wid & 1) * 32;
    f32x4 acc[2][2] = {};
    int sRow = t >> 2;        // 0..63
    int sK = (t & 3) * 8;     // 0,8,16,24
    int lr = lane & 15;
    int kg = (lane >> 4) * 8;

    for (int k0 = 0; k0 < K; k0 += 32) {
        int gr = row0 + sRow;
        uint4 av = {0u, 0u, 0u, 0u};
        if (gr < M) av = *(const uint4*)(A + (size_t)gr * K + k0 + sK);
        *(uint4*)(&Asl[sRow * LDK + sK]) = av;
        uint4 bv = *(const uint4*)(Bt + (size_t)(col0 + sRow) * K + k0 + sK);
        *(uint4*)(&Bsl[sRow * LDK + sK]) = bv;
        __syncthreads();
        short8v a0 = *(const short8v*)(&Asl[(wr + lr) * LDK + kg]);
        short8v a1 = *(const short8v*)(&Asl[(wr + 16 + lr) * LDK + kg]);
        short8v b0 = *(const short8v*)(&Bsl[(wc + lr) * LDK + kg]);
        short8v b1 = *(const short8v*)(&Bsl[(wc + 16 + lr) * LDK + kg]);
        acc[0][0] = __builtin_amdgcn_mfma_f32_16x16x32_bf16(a0, b0, acc[0][0], 0, 0, 0);
        acc[0][1] = __builtin_amdgcn_mfma_f32_16x16x32_bf16(a0, b1, acc[0][1], 0, 0, 0);
        acc[1][0] = __builtin_amdgcn_mfma_f32_16x16x32_bf16(a1, b0, acc[1][0], 0, 0, 0);
        acc[1][1] = __builtin_amdgcn_mfma_f32_16x16x32_bf16(a1, b1, acc[1][1], 0, 0, 0);
        __syncthreads();
    }
    // C/D layout: col = lane&15, row = (lane>>4)*4 + j   [m89-verified]
#pragma unroll
    for (int mf = 0; mf < 2; ++mf) {
#pragma unroll
        for (int nf = 0; nf < 2; ++nf) {
            int c = col0 + wc + nf * 16 + lr;
            float bb = bias ? bias[c] : 0.f;
#pragma unroll
            for (int j = 0; j < 4; ++j) {
                int r = row0 + wr + mf * 16 + (lane >> 4) * 4 + j;
                if (r < M) C[(size_t)r * CH + c] = f2bf(acc[mf][nf][j] + bb);
            }
        }
    }
}

// ---------------- LN + ELU on bf16 (128 thr, 4 ch/thread) ----------------
__global__ __launch_bounds__(128) void ln_elu_k(const ushort* __restrict__ inb, const float* __restrict__ g,
                                                const float* __restrict__ b, ushort* __restrict__ outb) {
    int i = blockIdx.x, t = threadIdx.x;
    uint2 hv = ((const uint2*)(inb + (size_t)i * CH))[t];
    float a0 = bf2f(hv.x & 0xffff), a1 = bf2f(hv.x >> 16);
    float a2 = bf2f(hv.y & 0xffff), a3 = bf2f(hv.y >> 16);
    float s = a0 + a1 + a2 + a3;
    float s2 = a0 * a0 + a1 * a1 + a2 * a2 + a3 * a3;
#pragma unroll
    for (int off = 1; off < 64; off <<= 1) { s += __shfl_xor(s, off); s2 += __shfl_xor(s2, off); }
    __shared__ float sh[4];
    int wid = t >> 6, lane = t & 63;
    if (lane == 0) { sh[wid] = s; sh[2 + wid] = s2; }
    __syncthreads();
    float tot = sh[0] + sh[1], tot2 = sh[2] + sh[3];
    float mean = tot * (1.0f / CH);
    float var = tot2 * (1.0f / CH) - mean * mean;
    float rstd = rsqrtf(var + 1e-5f);
    float4 gv = ((const float4*)g)[t];
    float4 bv = ((const float4*)b)[t];
    float y0 = (a0 - mean) * rstd * gv.x + bv.x; y0 = y0 > 0.f ? y0 : __expf(y0) - 1.f;
    float y1 = (a1 - mean) * rstd * gv.y + bv.y; y1 = y1 > 0.f ? y1 : __expf(y1) - 1.f;
    float y2 = (a2 - mean) * rstd * gv.z + bv.z; y2 = y2 > 0.f ? y2 : __expf(y2) - 1.f;
    float y3 = (a3 - mean) * rstd * gv.w + bv.w; y3 = y3 > 0.f ? y3 : __expf(y3) - 1.f;
    ushort4 o; o.x = f2bf(y0); o.y = f2bf(y1); o.z = f2bf(y2); o.w = f2bf(y3);
    ((ushort4*)(outb + (size_t)i * CH))[t] = o;
}

// ---------------- attention logits (8 heads, bf16 h) ----------------
__global__ void attn_logits_k(const ushort* __restrict__ h, const float* __restrict__ a_src,
                              const float* __restrict__ a_dst, float* __restrict__ als,
                              float* __restrict__ ald) {
    int idx = blockIdx.x * 256 + threadIdx.x;
    if (idx >= NNODES * NHEAD) return;
    int i = idx >> 3, hh = idx & 7;
    const uint2* hp = (const uint2*)(h + (size_t)i * CH + hh * HDIM);
    const float* sp = a_src + hh * HDIM;
    const float* dp = a_dst + hh * HDIM;
    float s = 0.f, d = 0.f;
#pragma unroll
    for (int j = 0; j < HDIM / 4; ++j) {
        uint2 v = hp[j];
        float h0 = bf2f(v.x & 0xffff), h1 = bf2f(v.x >> 16);
        float h2 = bf2f(v.y & 0xffff), h3 = bf2f(v.y >> 16);
        s += h0 * sp[j * 4] + h1 * sp[j * 4 + 1] + h2 * sp[j * 4 + 2] + h3 * sp[j * 4 + 3];
        d += h0 * dp[j * 4] + h1 * dp[j * 4 + 1] + h2 * dp[j * 4 + 2] + h3 * dp[j * 4 + 3];
    }
    als[idx] = s; ald[idx] = d;
}

// -------- FUSED one-pass online-softmax gather + bias + LN + ELU + residual -----------
// block = 1 node, 128 thr, 4 ch/thread; head group = 16 threads sharing identical m/s state
__global__ __launch_bounds__(128) void agg_ln_k(const ushort* __restrict__ hb, const float* __restrict__ als,
                                                const float* __restrict__ ald, const int* __restrict__ startA,
                                                const int* __restrict__ deg, const int* __restrict__ csr,
                                                const float* __restrict__ bias, const float* __restrict__ gamma,
                                                const float* __restrict__ beta, const ushort* __restrict__ residb,
                                                ushort* __restrict__ outb) {
    int i = blockIdx.x, t = threadIdx.x;
    int c0 = t * 4, head = t >> 4;
    int s0 = startA[i], d = deg[i];
    float aldv = ald[i * NHEAD + head];
    const int* cp = csr + s0;
    float m = -1e30f, ssum = 0.f;
    float a0 = 0.f, a1 = 0.f, a2 = 0.f, a3 = 0.f;
    for (int e = 0; e < d; ++e) {
        int src = cp[e];
        float ee = als[src * NHEAD + head] + aldv;
        ee = ee > 0.f ? ee : NEG_SLOPE * ee;
        float p;
        if (ee > m) {  // online rescale (uniform within each 16-thread head group)
            float scale = __expf(m - ee);
            ssum *= scale; a0 *= scale; a1 *= scale; a2 *= scale; a3 *= scale;
            m = ee; p = 1.0f;
        } else {
            p = __expf(ee - m);
        }
        ssum += p;
        uint2 hv = *(const uint2*)(hb + (size_t)src * CH + c0);
        a0 += p * bf2f(hv.x & 0xffff); a1 += p * bf2f(hv.x >> 16);
        a2 += p * bf2f(hv.y & 0xffff); a3 += p * bf2f(hv.y >> 16);
    }
    float inv = 1.0f / (ssum + 1e-16f);
    float4 bi = ((const float4*)bias)[t];
    a0 = a0 * inv + bi.x; a1 = a1 * inv + bi.y; a2 = a2 * inv + bi.z; a3 = a3 * inv + bi.w;
    float s = a0 + a1 + a2 + a3;
    float s2 = a0 * a0 + a1 * a1 + a2 * a2 + a3 * a3;
#pragma unroll
    for (int off = 1; off < 64; off <<= 1) { s += __shfl_xor(s, off); s2 += __shfl_xor(s2, off); }
    __shared__ float sh[4];
    int wid = t >> 6, lane = t & 63;
    if (lane == 0) { sh[wid] = s; sh[2 + wid] = s2; }
    __syncthreads();
    float tot = sh[0] + sh[1], tot2 = sh[2] + sh[3];
    float mean = tot * (1.0f / CH);
    float var = tot2 * (1.0f / CH) - mean * mean;
    float rstd = rsqrtf(var + 1e-5f);
    float4 gv = ((const float4*)gamma)[t];
    float4 bv = ((const float4*)beta)[t];
    uint2 rv = ((const uint2*)(residb + (size_t)i * CH))[t];
    float y0 = (a0 - mean) * rstd * gv.x + bv.x; y0 = (y0 > 0.f ? y0 : __expf(y0) - 1.f) + bf2f(rv.x & 0xffff);
    float y1 = (a1 - mean) * rstd * gv.y + bv.y; y1 = (y1 > 0.f ? y1 : __expf(y1) - 1.f) + bf2f(rv.x >> 16);
    float y2 = (a2 - mean) * rstd * gv.z + bv.z; y2 = (y2 > 0.f ? y2 : __expf(y2) - 1.f) + bf2f(rv.y & 0xffff);
    float y3 = (a3 - mean) * rstd * gv.w + bv.w; y3 = (y3 > 0.f ? y3 : __expf(y3) - 1.f) + bf2f(rv.y >> 16);
    ushort4 o; o.x = f2bf(y0); o.y = f2bf(y1); o.z = f2bf(y2); o.w = f2bf(y3);
    ((ushort4*)(outb + (size_t)i * CH))[t] = o;
}

// ---------------- small GEMM: h3[M,16] = A[M,512](bf16) @ W3[512,16](fp32) ----------------
__global__ __launch_bounds__(256) void gemm_small_k(const ushort* __restrict__ A, const float* __restrict__ W,
                                                    float* __restrict__ C) {
    int col = threadIdx.x & 15;
    int row = blockIdx.x * 16 + (threadIdx.x >> 4);
    if (row >= NNODES) return;
    const ushort* ar = A + (size_t)row * CH;
    float acc = 0.f;
#pragma unroll 8
    for (int k = 0; k < CH; k += 2) {
        uint av = *(const uint*)(ar + k);
        acc += bf2f(av & 0xffff) * W[k * COUT + col];
        acc += bf2f(av >> 16) * W[(k + 1) * COUT + col];
    }
    C[row * COUT + col] = acc;
}

// -------- FUSED final layer: logits + online softmax + gather + bias + LN (16 ch) --------
// 256 thr = 16 nodes x 16 ch; h3[src] row loaded once, used for logit dot AND accumulation
__global__ __launch_bounds__(256) void agg16f_k(const float* __restrict__ h3, const float* __restrict__ as3,
                                                const float* __restrict__ ad3, const int* __restrict__ startA,
                                                const int* __restrict__ deg, const int* __restrict__ csr,
                                                const float* __restrict__ b3, const float* __restrict__ g3,
                                                const float* __restrict__ be3, float* __restrict__ out) {
    int t = threadIdx.x;
    int i = blockIdx.x * 16 + (t >> 4);
    int c = t & 15;
    if (i >= NNODES) return;
    float asc = as3[c], adc = ad3[c];
    // ald_i = h3[i] . ad3  (width-16 shuffle reduce)
    float ald_i = h3[i * COUT + c] * adc;
#pragma unroll
    for (int off = 1; off < 16; off <<= 1) ald_i += __shfl_xor(ald_i, off, 16);
    int s0 = startA[i], d = deg[i];
    float m = -1e30f, ssum = 0.f, acc = 0.f;
    for (int e = 0; e < d; ++e) {
        int src = csr[s0 + e];
        float v = h3[src * COUT + c];
        float al = v * asc;
#pragma unroll
        for (int off = 1; off < 16; off <<= 1) al += __shfl_xor(al, off, 16);
        float ee = al + ald_i;
        ee = ee > 0.f ? ee : NEG_SLOPE * ee;
        float p;
        if (ee > m) {
            float scale = __expf(m - ee);
            ssum *= scale; acc *= scale;
            m = ee; p = 1.0f;
        } else {
            p = __expf(ee - m);
        }
        ssum += p;
        acc += p * v;
    }
    acc = acc / (ssum + 1e-16f) + b3[c];
    float v = acc, v2 = acc * acc;
#pragma unroll
    for (int off = 1; off < 16; off <<= 1) { v += __shfl_xor(v, off, 16); v2 += __shfl_xor(v2, off, 16); }
    float mean = v * (1.0f / COUT);
    float var = v2 * (1.0f / COUT) - mean * mean;
    out[i * COUT + c] = (acc - mean) * rsqrtf(var + 1e-5f) * g3[c] + be3[c];
}

extern "C" void kernel_launch(void* const* d_in, const int* in_sizes, int n_in,
                              void* d_out, int out_size, void* d_ws, size_t ws_size,
                              hipStream_t stream) {
    const float* x   = (const float*)d_in[0];
    const int*   ei  = (const int*)d_in[1];
    const float* Wp  = (const float*)d_in[2];
    const float* bp  = (const float*)d_in[3];
    const float* g0  = (const float*)d_in[4];
    const float* b0  = (const float*)d_in[5];
    const float* W1  = (const float*)d_in[6];
    const float* as1 = (const float*)d_in[7];
    const float* ad1 = (const float*)d_in[8];
    const float* b1  = (const float*)d_in[9];
    const float* g1  = (const float*)d_in[10];
    const float* be1 = (const float*)d_in[11];
    const float* W2  = (const float*)d_in[12];
    const float* as2 = (const float*)d_in[13];
    const float* ad2 = (const float*)d_in[14];
    const float* b2  = (const float*)d_in[15];
    const float* g2  = (const float*)d_in[16];
    const float* be2 = (const float*)d_in[17];
    const float* W3  = (const float*)d_in[18];
    const float* as3 = (const float*)d_in[19];
    const float* ad3 = (const float*)d_in[20];
    const float* b3  = (const float*)d_in[21];
    const float* g3  = (const float*)d_in[22];
    const float* be3 = (const float*)d_in[23];

    // ---- workspace carve (~40 MB) ----
    ushort* B0  = (ushort*)d_ws;           // NF bf16 activations (rotating)
    ushort* B1  = B0 + NF;
    ushort* B2  = B1 + NF;
    ushort* xbf = B2 + NF;                 // NNODES*CIN
    ushort* Wpt = xbf + (size_t)NNODES * CIN;   // CIN*CH
    ushort* W1t = Wpt + (size_t)CIN * CH;       // CH*CH
    ushort* W2t = W1t + (size_t)CH * CH;
    float* als = (float*)(W2t + (size_t)CH * CH);
    float* ald = als + NNODES * NHEAD;
    float* h3  = ald + NNODES * NHEAD;          // NNODES*COUT
    int* deg = (int*)(h3 + (size_t)NNODES * COUT);
    int* stA = deg + NNODES;
    int* cur = stA + NNODES;
    int* csr = cur + NNODES;

    // ---- CSR build ----
    hipMemsetAsync(deg, 0, NNODES * sizeof(int), stream);
    hipMemsetAsync(cur, 0, NNODES * sizeof(int), stream);
    count_deg_k<<<(ETOT + 255) / 256, 256, 0, stream>>>(ei, deg);
    scan_k<<<1, 512, 0, stream>>>(deg, stA);
    scatter_k<<<(ETOT + 255) / 256, 256, 0, stream>>>(ei, stA, cur, csr);

    // ---- converts ----
    convert_x_k<<<(NNODES * CIN / 4 + 255) / 256, 256, 0, stream>>>(x, xbf);
    convert_wT_k<<<dim3(CH / 32, CIN / 32), 256, 0, stream>>>(Wp, Wpt, CIN, CH);
    convert_wT_k<<<dim3(CH / 32, CH / 32), 256, 0, stream>>>(W1, W1t, CH, CH);
    convert_wT_k<<<dim3(CH / 32, CH / 32), 256, 0, stream>>>(W2, W2t, CH, CH);

    dim3 gg((NNODES + 63) / 64, CH / 64);

    // ---- input projection + LN + ELU ----
    gemm_mfma<<<gg, 256, 0, stream>>>(xbf, Wpt, bp, B0, NNODES, CIN);
    ln_elu_k<<<NNODES, 128, 0, stream>>>(B0, g0, b0, B1);

    // ---- GAT layer 1: h=gemm(B1) -> B2; fused agg(resid=B1) -> B0 ----
    gemm_mfma<<<gg, 256, 0, stream>>>(B1, W1t, nullptr, B2, NNODES, CH);
    attn_logits_k<<<(NNODES * NHEAD + 255) / 256, 256, 0, stream>>>(B2, as1, ad1, als, ald);
    agg_ln_k<<<NNODES, 128, 0, stream>>>(B2, als, ald, stA, deg, csr, b1, g1, be1, B1, B0);

    // ---- GAT layer 2: h=gemm(B0) -> B1; fused agg(resid=B0) -> B2 ----
    gemm_mfma<<<gg, 256, 0, stream>>>(B0, W2t, nullptr, B1, NNODES, CH);
    attn_logits_k<<<(NNODES * NHEAD + 255) / 256, 256, 0, stream>>>(B1, as2, ad2, als, ald);
    agg_ln_k<<<NNODES, 128, 0, stream>>>(B1, als, ald, stA, deg, csr, b2, g2, be2, B0, B2);

    // ---- final layer (B2 -> d_out): small GEMM + fully fused attention ----
    gemm_small_k<<<(NNODES + 15) / 16, 256, 0, stream>>>(B2, W3, h3);
    agg16f_k<<<(NNODES + 15) / 16, 256, 0, stream>>>(h3, as3, ad3, stA, deg, csr, b3, g3, be3, (float*)d_out);
}